// Round 5
// baseline (434.975 us; speedup 1.0000x reference)
//
#include <hip/hip_runtime.h>
#include <hip/hip_bf16.h>
#include <cmath>

// Problem constants
constexpr int Bn  = 4;
constexpr int Sn  = 4096;
constexpr int En  = 1024;
constexpr int Hn  = 16;
constexpr int HD  = 64;
constexpr int WSZ = 128;
constexpr int NW  = Sn / WSZ;   // 32
constexpr int Mr  = Bn * Sn;    // 16384 rows
constexpr int N3  = 3 * En;     // 3072
constexpr int Kd  = En;         // 1024

typedef __attribute__((ext_vector_type(8))) short  bf16x8;
typedef __attribute__((ext_vector_type(4))) float  f32x4;
typedef __attribute__((ext_vector_type(8))) unsigned short ushort8;

__device__ __forceinline__ unsigned short f2bf(float f) {
  __hip_bfloat16 h = __float2bfloat16(f);   // RTNE
  return *reinterpret_cast<unsigned short*>(&h);
}

__device__ __forceinline__ void gload_lds16(const void* g, void* l) {
  __builtin_amdgcn_global_load_lds(
      (const __attribute__((address_space(1))) void*)g,
      (__attribute__((address_space(3))) void*)l, 16, 0, 0);
}

// ---------------------------------------------------------------------------
// cvt_x: x fp32 [16384,1024] -> bf16 (row-major)
// ---------------------------------------------------------------------------
__global__ __launch_bounds__(256) void cvt_x(const float* __restrict__ x,
                                             unsigned short* __restrict__ xb) {
  const int i = (blockIdx.x * 256 + threadIdx.x) * 8;
  const float4 a = *(const float4*)&x[i];
  const float4 b = *(const float4*)&x[i + 4];
  ushort8 o;
  o[0] = f2bf(a.x); o[1] = f2bf(a.y); o[2] = f2bf(a.z); o[3] = f2bf(a.w);
  o[4] = f2bf(b.x); o[5] = f2bf(b.y); o[6] = f2bf(b.z); o[7] = f2bf(b.w);
  *(ushort8*)&xb[i] = o;
}

// ---------------------------------------------------------------------------
// cvt_wT: W fp32 [K=1024][N=3072] -> Wt bf16 [N=3072][K=1024]  (transpose)
// ---------------------------------------------------------------------------
__global__ __launch_bounds__(256) void cvt_wT(const float* __restrict__ W,
                                              unsigned short* __restrict__ Wt) {
  __shared__ float t[32][33];
  const int bx = blockIdx.x * 32;          // n base
  const int by = blockIdx.y * 32;          // k base
  const int tx = threadIdx.x & 31;
  const int ty = threadIdx.x >> 5;
  #pragma unroll
  for (int i = 0; i < 32; i += 8)
    t[ty + i][tx] = W[(size_t)(by + ty + i) * N3 + bx + tx];
  __syncthreads();
  #pragma unroll
  for (int i = 0; i < 32; i += 8)
    Wt[(size_t)(bx + ty + i) * Kd + by + tx] = f2bf(t[tx][ty + i]);
}

// ---------------------------------------------------------------------------
// cvt_vT: Vb bf16 [bh][s][64] -> VT bf16 [bh][64][s]  (per-head transpose)
// ---------------------------------------------------------------------------
__global__ __launch_bounds__(256) void cvt_vT(const unsigned short* __restrict__ V,
                                              unsigned short* __restrict__ VT) {
  __shared__ unsigned short t[64][72];
  const int s0 = blockIdx.x * 64;
  const int bh = blockIdx.y;
  const unsigned short* Vg = V + ((size_t)bh * Sn + s0) * HD;
  const int r  = threadIdx.x >> 3;          // 0..31
  const int c8 = (threadIdx.x & 7) * 8;
  *(ushort8*)&t[r][c8]      = *(const ushort8*)&Vg[(size_t)r * HD + c8];
  *(ushort8*)&t[r + 32][c8] = *(const ushort8*)&Vg[(size_t)(r + 32) * HD + c8];
  __syncthreads();
  unsigned short* Og = VT + (size_t)bh * HD * Sn + s0;
  const int d = threadIdx.x >> 3;           // 0..31
  ushort8 o0, o1;
  #pragma unroll
  for (int j = 0; j < 8; ++j) { o0[j] = t[c8 + j][d]; o1[j] = t[c8 + j][d + 32]; }
  *(ushort8*)&Og[(size_t)d * Sn + c8]        = o0;
  *(ushort8*)&Og[(size_t)(d + 32) * Sn + c8] = o1;
}

// ---------------------------------------------------------------------------
// qkv_gemm_bf16 (m97 structure, unchanged — verified)
// ---------------------------------------------------------------------------
constexpr int TM = 128, TN = 128, TK = 32;

__global__ __launch_bounds__(256) void qkv_gemm_bf16(
    const unsigned short* __restrict__ Abf,   // [Mr][Kd]
    const unsigned short* __restrict__ Bt,    // [N3][Kd]
    const float* __restrict__ bias,
    unsigned short* __restrict__ Qb, unsigned short* __restrict__ Kb,
    unsigned short* __restrict__ Vb) {
  __shared__ unsigned short As[TM * TK];
  __shared__ unsigned short Bs[TN * TK];

  const int tid  = threadIdx.x;
  const int wave = tid >> 6;
  const int lane = tid & 63;
  const int bm = blockIdx.y * TM;
  const int bn = blockIdx.x * TN;
  const int wr = wave >> 1, wc = wave & 1;

  f32x4 acc[4][4] = {};

  const int sr  = lane >> 2;
  const int sc8 = (lane & 3) * 8;
  const int fr = lane & 15;
  const int fk = (lane >> 4) * 8;

  for (int k0 = 0; k0 < Kd; k0 += TK) {
    #pragma unroll
    for (int i = 0; i < 2; ++i) {
      const int c = wave * 2 + i;
      gload_lds16(Abf + (size_t)(bm + c * 16 + sr) * Kd + k0 + sc8, &As[c * 512]);
      gload_lds16(Bt  + (size_t)(bn + c * 16 + sr) * Kd + k0 + sc8, &Bs[c * 512]);
    }
    __syncthreads();
    bf16x8 af[4], bfr[4];
    #pragma unroll
    for (int m = 0; m < 4; ++m)
      af[m] = *(const bf16x8*)&As[(wr * 64 + m * 16 + fr) * TK + fk];
    #pragma unroll
    for (int n = 0; n < 4; ++n)
      bfr[n] = *(const bf16x8*)&Bs[(wc * 64 + n * 16 + fr) * TK + fk];
    #pragma unroll
    for (int m = 0; m < 4; ++m)
      #pragma unroll
      for (int n = 0; n < 4; ++n)
        acc[m][n] = __builtin_amdgcn_mfma_f32_16x16x32_bf16(
            af[m], bfr[n], acc[m][n], 0, 0, 0);
    __syncthreads();
  }

  const int col0 = bn + wc * 64 + (lane & 15);
  const int row0 = bm + wr * 64 + (lane >> 4) * 4;
  #pragma unroll
  for (int n = 0; n < 4; ++n) {
    const int col = col0 + n * 16;
    const float bv = bias[col];
    const int which = col >> 10;           // 0=q 1=k 2=v (wave-uniform)
    const int h = (col >> 6) & 15;
    const int d = col & 63;
    unsigned short* T = (which == 0) ? Qb : (which == 1) ? Kb : Vb;
    #pragma unroll
    for (int m = 0; m < 4; ++m)
      #pragma unroll
      for (int r = 0; r < 4; ++r) {
        const int row = row0 + m * 16 + r;
        const int b = row >> 12;
        const int s = row & 4095;
        T[((size_t)((b << 4) + h) * Sn + s) * HD + d] =
            f2bf(acc[m][n][r] + bv);
      }
  }
}

// ---------------------------------------------------------------------------
// attn_mfma: flash-style local attention, MFMA 16x16x32 bf16.
// R5: Ps stride-64 + XOR swizzle (LDS 48K -> 3 blocks/CU); T13 defer-max
// (skip rescale when wave-wide max growth <= 8; P bounded by e^8).
// ---------------------------------------------------------------------------
__global__ __launch_bounds__(256) void attn_mfma(
    const unsigned short* __restrict__ Qb,
    const unsigned short* __restrict__ Kb,
    const unsigned short* __restrict__ VT,
    float* __restrict__ out) {
  __shared__ unsigned short Ks[2][64 * 64];   // 16 KB (rows = key)
  __shared__ unsigned short Vs[2][64 * 64];   // 16 KB (rows = d)
  __shared__ unsigned short Ps[4][32 * 64];   // 16 KB (swizzled, per-wave)

  const int w   = blockIdx.x;
  const int bh  = blockIdx.y;
  const int tid = threadIdx.x, wave = tid >> 6, lane = tid & 63;
  const int gl = lane >> 4, li = lane & 15;
  const int q0 = wave * 32;

  const size_t head_off = (size_t)bh * Sn * HD;
  const unsigned short* Qg  = Qb + head_off + (size_t)w * WSZ * HD;
  const unsigned short* Kg0 = Kb + head_off;
  const unsigned short* Vg0 = VT + (size_t)bh * HD * Sn;

  // --- Q fragments in registers ---
  bf16x8 qf[2][2];
  #pragma unroll
  for (int m = 0; m < 2; ++m)
    #pragma unroll
    for (int ks = 0; ks < 2; ++ks)
      qf[m][ks] = *(const bf16x8*)
          &Qg[(size_t)(q0 + m * 16 + li) * HD + ks * 32 + gl * 8];

  bf16x8 ones;
  #pragma unroll
  for (int j = 0; j < 8; ++j) ones[j] = (short)0x3F80;   // bf16 1.0
  f32x4 qsum[2] = {};
  #pragma unroll
  for (int m = 0; m < 2; ++m)
    #pragma unroll
    for (int ks = 0; ks < 2; ++ks)
      qsum[m] = __builtin_amdgcn_mfma_f32_16x16x32_bf16(
          qf[m][ks], ones, qsum[m], 0, 0, 0);

  f32x4 acc[2][4] = {};
  float m_run[2][4], l_run[2][4];
  #pragma unroll
  for (int m = 0; m < 2; ++m)
    #pragma unroll
    for (int r = 0; r < 4; ++r) { m_run[m][r] = -3e38f; l_run[m][r] = 0.f; }

  // --- pad windows (reference: 128 unmasked all-(-1) K/V rows) ---
  if (w == 0 || w == NW - 1) {
    #pragma unroll
    for (int m = 0; m < 2; ++m)
      #pragma unroll
      for (int r = 0; r < 4; ++r) {
        const float sp = -qsum[m][r];
        const float mn = fmaxf(m_run[m][r], sp);
        const float scale = __expf(m_run[m][r] - mn);
        const float pe = __expf(sp - mn) * 128.f;
        l_run[m][r] = l_run[m][r] * scale + pe;
        m_run[m][r] = mn;
        #pragma unroll
        for (int nd = 0; nd < 4; ++nd)
          acc[m][nd][r] = acc[m][nd][r] * scale - pe;
      }
  }

  // valid neighbor windows
  int vw[3], nv = 0;
  #pragma unroll
  for (int c = 0; c < 3; ++c) {
    const int wk = w + c - 1;
    if (0 <= wk && wk < NW) vw[nv++] = wk;
  }
  const int T = 2 * nv;

  const int rsub  = lane >> 3;
  const int ebsub = ((lane & 7) ^ rsub) * 8;   // pre-swizzled elem offset

  auto stage = [&](int t, int buf) {
    const int wk = vw[t >> 1];
    const int s0 = wk * WSZ + (t & 1) * 64;
    #pragma unroll
    for (int i = 0; i < 2; ++i) {
      const int cc = wave * 2 + i;
      gload_lds16(Kg0 + (size_t)(s0 + cc * 8 + rsub) * HD + ebsub,
                  &Ks[buf][cc * 512]);
      gload_lds16(Vg0 + (size_t)(cc * 8 + rsub) * Sn + s0 + ebsub,
                  &Vs[buf][cc * 512]);
    }
  };

  // swizzled frag read: row-major [row][64] bf16, XOR ((row&7)<<4)
  auto lds_frag = [&](const unsigned short* base, int row, int kpos) {
    return *(const bf16x8*)((const char*)base + row * 128 +
                            ((kpos * 2) ^ ((row & 7) << 4)));
  };

  unsigned short* Psw = &Ps[wave][0];

  stage(0, 0);
  __syncthreads();

  for (int t = 0; t < T; ++t) {
    const int buf = t & 1;
    if (t + 1 < T) stage(t + 1, buf ^ 1);   // in flight during compute

    const int wk = vw[t >> 1];
    const int c  = wk - w + 1;              // 0,1,2
    const int ch = t & 1;

    // --- QK^T ---
    f32x4 s[2][4] = {};
    __builtin_amdgcn_s_setprio(1);
    #pragma unroll
    for (int ks = 0; ks < 2; ++ks) {
      #pragma unroll
      for (int n = 0; n < 4; ++n) {
        const bf16x8 bk = lds_frag(&Ks[buf][0], n * 16 + li, ks * 32 + gl * 8);
        s[0][n] = __builtin_amdgcn_mfma_f32_16x16x32_bf16(qf[0][ks], bk, s[0][n], 0, 0, 0);
        s[1][n] = __builtin_amdgcn_mfma_f32_16x16x32_bf16(qf[1][ks], bk, s[1][n], 0, 0, 0);
      }
    }
    __builtin_amdgcn_s_setprio(0);

    // --- mask ---
    if (c != 1) {
      #pragma unroll
      for (int m = 0; m < 2; ++m)
        #pragma unroll
        for (int n = 0; n < 4; ++n)
          #pragma unroll
          for (int r = 0; r < 4; ++r) {
            const int q_in = q0 + m * 16 + gl * 4 + r;
            const int k_in = ch * 64 + n * 16 + li;
            const bool bad = (c == 0) ? (k_in < q_in) : (k_in > q_in);
            if (bad) s[m][n][r] = -3e38f;
          }
    }

    // --- online softmax: row max (16-lane group owns a row) ---
    float mx[2][4];
    #pragma unroll
    for (int m = 0; m < 2; ++m) {
      #pragma unroll
      for (int r = 0; r < 4; ++r)
        mx[m][r] = fmaxf(fmaxf(s[m][0][r], s[m][1][r]),
                         fmaxf(s[m][2][r], s[m][3][r]));
      #pragma unroll
      for (int off = 1; off < 16; off <<= 1)
        #pragma unroll
        for (int r = 0; r < 4; ++r)
          mx[m][r] = fmaxf(mx[m][r], __shfl_xor(mx[m][r], off));
    }

    // --- T13 defer-max: rescale only if wave-wide growth > 8 ---
    float growth = -3e38f;
    #pragma unroll
    for (int m = 0; m < 2; ++m)
      #pragma unroll
      for (int r = 0; r < 4; ++r)
        growth = fmaxf(growth, mx[m][r] - m_run[m][r]);
    if (__any(growth > 8.f)) {
      #pragma unroll
      for (int m = 0; m < 2; ++m)
        #pragma unroll
        for (int r = 0; r < 4; ++r) {
          const float mn = fmaxf(m_run[m][r], mx[m][r]);
          const float sc = __expf(m_run[m][r] - mn);
          m_run[m][r] = mn;
          l_run[m][r] *= sc;
          #pragma unroll
          for (int nd = 0; nd < 4; ++nd)
            acc[m][nd][r] *= sc;
        }
    }

    // --- P = exp(s - m_run), row sums ---
    #pragma unroll
    for (int m = 0; m < 2; ++m) {
      float rs[4] = {0.f, 0.f, 0.f, 0.f};
      #pragma unroll
      for (int n = 0; n < 4; ++n)
        #pragma unroll
        for (int r = 0; r < 4; ++r) {
          const float v = s[m][n][r];
          const float p = (v > -1e30f) ? __expf(v - m_run[m][r]) : 0.f;
          s[m][n][r] = p;
          rs[r] += p;
        }
      #pragma unroll
      for (int off = 1; off < 16; off <<= 1)
        #pragma unroll
        for (int r = 0; r < 4; ++r)
          rs[r] += __shfl_xor(rs[r], off);
      #pragma unroll
      for (int r = 0; r < 4; ++r)
        l_run[m][r] += rs[r];
    }

    // --- P -> LDS bf16 (stride 64, XOR swizzle; same involution as read) ---
    #pragma unroll
    for (int m = 0; m < 2; ++m)
      #pragma unroll
      for (int n = 0; n < 4; ++n)
        #pragma unroll
        for (int r = 0; r < 4; ++r) {
          const int row = m * 16 + gl * 4 + r;
          const int colb = (n * 16 + li) * 2;
          *(unsigned short*)((char*)Psw +
              row * 128 + (colb ^ ((row & 7) << 4))) = f2bf(s[m][n][r]);
        }

    // --- PV ---
    __builtin_amdgcn_s_setprio(1);
    #pragma unroll
    for (int ks = 0; ks < 2; ++ks) {
      const bf16x8 ap0 = lds_frag(Psw, li, ks * 32 + gl * 8);
      const bf16x8 ap1 = lds_frag(Psw, 16 + li, ks * 32 + gl * 8);
      #pragma unroll
      for (int nd = 0; nd < 4; ++nd) {
        const bf16x8 bv = lds_frag(&Vs[buf][0], nd * 16 + li, ks * 32 + gl * 8);
        acc[0][nd] = __builtin_amdgcn_mfma_f32_16x16x32_bf16(ap0, bv, acc[0][nd], 0, 0, 0);
        acc[1][nd] = __builtin_amdgcn_mfma_f32_16x16x32_bf16(ap1, bv, acc[1][nd], 0, 0, 0);
      }
    }
    __builtin_amdgcn_s_setprio(0);

    __syncthreads();   // drains next-chunk loads; releases buf for t+2 stage
  }

  // --- normalize + write out fp32 [b][s][h*64+d] ---
  const int b = bh >> 4, h = bh & 15;
  #pragma unroll
  for (int m = 0; m < 2; ++m) {
    float inv[4];
    #pragma unroll
    for (int r = 0; r < 4; ++r) inv[r] = 1.f / l_run[m][r];
    #pragma unroll
    for (int nd = 0; nd < 4; ++nd)
      #pragma unroll
      for (int r = 0; r < 4; ++r) {
        const int q = q0 + m * 16 + gl * 4 + r;
        out[((size_t)(b * Sn + w * WSZ + q)) * En + h * HD + nd * 16 + li] =
            acc[m][nd][r] * inv[r];
      }
  }
}

// ---------------------------------------------------------------------------
extern "C" void kernel_launch(void* const* d_in, const int* in_sizes, int n_in,
                              void* d_out, int out_size, void* d_ws,
                              size_t ws_size, hipStream_t stream) {
  const float* x    = (const float*)d_in[0];
  const float* wqkv = (const float*)d_in[1];
  const float* bqkv = (const float*)d_in[2];
  float* out = (float*)d_out;

  // ws layout (ushort units): Qb | Kb | Vb | VT | xb | wb  = ~174 MB
  unsigned short* ws = (unsigned short*)d_ws;
  const size_t HT = (size_t)Bn * Hn * Sn * HD;   // 16.78M elems per tensor
  unsigned short* Qb = ws;
  unsigned short* Kb = ws + HT;
  unsigned short* Vb = ws + 2 * HT;
  unsigned short* VTt = ws + 3 * HT;
  unsigned short* xb = ws + 4 * HT;
  unsigned short* wb = ws + 4 * HT + (size_t)Mr * Kd;

  cvt_x<<<(Mr * Kd) / (256 * 8), 256, 0, stream>>>(x, xb);
  dim3 gw(N3 / 32, Kd / 32);
  cvt_wT<<<gw, 256, 0, stream>>>(wqkv, wb);

  dim3 g1(N3 / TN, Mr / TM);
  qkv_gemm_bf16<<<g1, 256, 0, stream>>>(xb, wb, bqkv, Qb, Kb, Vb);

  dim3 gv(Sn / 64, Bn * Hn);
  cvt_vT<<<gv, 256, 0, stream>>>(Vb, VTt);

  dim3 g2(NW, Bn * Hn);
  attn_mfma<<<g2, 256, 0, stream>>>(Qb, Kb, VTt, out);
}